// Round 1
// baseline (2949.052 us; speedup 1.0000x reference)
//
#include <hip/hip_runtime.h>

#define N_NODES 50000
#define N_EDGES 800000
#define C 128
#define NPB 8  // nodes per block in layer1

// ---------------- degree count ----------------
__global__ void count_kernel(const int* __restrict__ dst, float* __restrict__ cnt) {
    int e = blockIdx.x * blockDim.x + threadIdx.x;
    if (e < N_EDGES) atomicAdd(&cnt[dst[e]], 1.0f);
}

// ---------------- edge scatter-add: agg[dst] += feat[src] ----------------
// one thread per (edge, 4-float chunk): 32 threads per edge
__global__ __launch_bounds__(256) void scatter_kernel(
    const int* __restrict__ src, const int* __restrict__ dst,
    const float* __restrict__ feat, float* __restrict__ agg) {
    long long tid = (long long)blockIdx.x * blockDim.x + threadIdx.x;
    int e = (int)(tid >> 5);
    if (e >= N_EDGES) return;
    int q = (int)(tid & 31);
    int s = src[e], d = dst[e];
    const float4 v = ((const float4*)(feat + (size_t)s * C))[q];
    float* base = agg + (size_t)d * C + q * 4;
    atomicAdd(base + 0, v.x);
    atomicAdd(base + 1, v.y);
    atomicAdd(base + 2, v.z);
    atomicAdd(base + 3, v.w);
}

// ---------------- layer 1: h = relu(mean @ W1l + b1l + x @ W1r) ----------------
// 128 threads (one per output col), 8 nodes per block, rows staged in LDS.
__global__ __launch_bounds__(128) void layer1_kernel(
    const float* __restrict__ x, const float* __restrict__ agg,
    const float* __restrict__ cnt, const float* __restrict__ W1l,
    const float* __restrict__ b1l, const float* __restrict__ W1r,
    float* __restrict__ h) {
    __shared__ float xs[NPB][C];
    __shared__ float ms[NPB][C];
    __shared__ float inv[NPB];
    int c = threadIdx.x;
    int n0 = blockIdx.x * NPB;
    if (c < NPB) {
        int node = n0 + c;
        float cv = (node < N_NODES) ? cnt[node] : 1.0f;
        inv[c] = 1.0f / fmaxf(cv, 1.0f);
    }
    __syncthreads();
    #pragma unroll
    for (int n = 0; n < NPB; n++) {
        int node = n0 + n;
        if (node < N_NODES) {
            xs[n][c] = x[(size_t)node * C + c];
            ms[n][c] = agg[(size_t)node * C + c] * inv[n];
        } else {
            xs[n][c] = 0.0f; ms[n][c] = 0.0f;
        }
    }
    __syncthreads();
    float bias = b1l[c];
    float acc[NPB];
    #pragma unroll
    for (int n = 0; n < NPB; n++) acc[n] = bias;
    for (int k = 0; k < C; k++) {
        float wl = W1l[k * C + c];
        float wr = W1r[k * C + c];
        #pragma unroll
        for (int n = 0; n < NPB; n++)
            acc[n] = fmaf(ms[n][k], wl, fmaf(xs[n][k], wr, acc[n]));
    }
    #pragma unroll
    for (int n = 0; n < NPB; n++) {
        int node = n0 + n;
        if (node < N_NODES)
            h[(size_t)node * C + c] = fmaxf(acc[n], 0.0f);
    }
}

// ---------------- layer 2: out = meanh @ W2l + b2l + h @ W2r ----------------
// one wave per node, shuffle reduce; 4 waves (4 nodes) per block.
__global__ __launch_bounds__(256) void layer2_kernel(
    const float* __restrict__ h, const float* __restrict__ agg,
    const float* __restrict__ cnt, const float* __restrict__ W2l,
    const float* __restrict__ b2l, const float* __restrict__ W2r,
    float* __restrict__ out) {
    int lane = threadIdx.x & 63;
    int wid  = threadIdx.x >> 6;
    int node = blockIdx.x * 4 + wid;
    if (node >= N_NODES) return;
    float invc = 1.0f / fmaxf(cnt[node], 1.0f);
    float a0 = 0.0f, a1 = 0.0f;
    #pragma unroll
    for (int t = 0; t < 2; t++) {
        int k = lane + 64 * t;
        float mh = agg[(size_t)node * C + k] * invc;
        float hv = h[(size_t)node * C + k];
        a0 = fmaf(mh, W2l[k * 2 + 0], fmaf(hv, W2r[k * 2 + 0], a0));
        a1 = fmaf(mh, W2l[k * 2 + 1], fmaf(hv, W2r[k * 2 + 1], a1));
    }
    #pragma unroll
    for (int off = 32; off > 0; off >>= 1) {
        a0 += __shfl_down(a0, off);
        a1 += __shfl_down(a1, off);
    }
    if (lane == 0) {
        out[node * 2 + 0] = a0 + b2l[0];
        out[node * 2 + 1] = a1 + b2l[1];
    }
}

extern "C" void kernel_launch(void* const* d_in, const int* in_sizes, int n_in,
                              void* d_out, int out_size, void* d_ws, size_t ws_size,
                              hipStream_t stream) {
    const float* x   = (const float*)d_in[0];
    const int*   ei  = (const int*)d_in[1];   // (2, 800000) row-major
    const float* W1l = (const float*)d_in[2];
    const float* b1l = (const float*)d_in[3];
    const float* W1r = (const float*)d_in[4];
    const float* W2l = (const float*)d_in[5];
    const float* b2l = (const float*)d_in[6];
    const float* W2r = (const float*)d_in[7];
    float* out = (float*)d_out;

    const int* src = ei;
    const int* dst = ei + N_EDGES;

    // workspace layout (floats): cnt[51200] | agg[50000*128] | h[50000*128]
    float* ws  = (float*)d_ws;
    float* cnt = ws;
    float* agg = ws + 51200;
    float* h   = ws + 51200 + (size_t)N_NODES * C;

    hipMemsetAsync(cnt, 0, (size_t)N_NODES * sizeof(float), stream);
    hipMemsetAsync(agg, 0, (size_t)N_NODES * C * sizeof(float), stream);

    count_kernel<<<(N_EDGES + 255) / 256, 256, 0, stream>>>(dst, cnt);

    // layer 1 aggregation + transform
    {
        long long total = (long long)N_EDGES * 32;
        int blocks = (int)((total + 255) / 256);
        scatter_kernel<<<blocks, 256, 0, stream>>>(src, dst, x, agg);
    }
    layer1_kernel<<<N_NODES / NPB, 128, 0, stream>>>(x, agg, cnt, W1l, b1l, W1r, h);

    // layer 2 aggregation + transform
    hipMemsetAsync(agg, 0, (size_t)N_NODES * C * sizeof(float), stream);
    {
        long long total = (long long)N_EDGES * 32;
        int blocks = (int)((total + 255) / 256);
        scatter_kernel<<<blocks, 256, 0, stream>>>(src, dst, h, agg);
    }
    layer2_kernel<<<(N_NODES + 3) / 4, 256, 0, stream>>>(h, agg, cnt, W2l, b2l, W2r, out);
}

// Round 2
// 568.489 us; speedup vs baseline: 5.1875x; 5.1875x over previous
//
#include <hip/hip_runtime.h>

#define N_NODES 50000
#define N_EDGES 800000
#define C 128
#define NPB 8  // nodes per block in layer1

// ---------------- degree histogram (int) ----------------
__global__ void hist_kernel(const int* __restrict__ dst, int* __restrict__ deg) {
    int e = blockIdx.x * blockDim.x + threadIdx.x;
    if (e < N_EDGES) atomicAdd(&deg[dst[e]], 1);
}

// ---------------- exclusive scan of deg -> row_ptr (single block) ----------------
__global__ __launch_bounds__(256) void scan_kernel(const int* __restrict__ deg,
                                                   int* __restrict__ row_ptr) {
    __shared__ int sums[256];
    const int PER = (N_NODES + 255) / 256;  // 196
    int t = threadIdx.x;
    int base = t * PER;
    int s = 0;
    for (int i = 0; i < PER; i++) {
        int idx = base + i;
        if (idx < N_NODES) s += deg[idx];
    }
    sums[t] = s;
    __syncthreads();
    // inclusive Hillis-Steele scan in LDS
    for (int off = 1; off < 256; off <<= 1) {
        int v = (t >= off) ? sums[t - off] : 0;
        __syncthreads();
        sums[t] += v;
        __syncthreads();
    }
    int run = (t == 0) ? 0 : sums[t - 1];
    for (int i = 0; i < PER; i++) {
        int idx = base + i;
        if (idx < N_NODES) { row_ptr[idx] = run; run += deg[idx]; }
    }
    if (t == 255) row_ptr[N_NODES] = run;
}

// ---------------- bucket fill: esorted[row_ptr[d] + pos] = src ----------------
__global__ void bucket_kernel(const int* __restrict__ src, const int* __restrict__ dst,
                              const int* __restrict__ row_ptr, int* __restrict__ cursor,
                              int* __restrict__ esorted) {
    int e = blockIdx.x * blockDim.x + threadIdx.x;
    if (e < N_EDGES) {
        int d = dst[e];
        int pos = atomicAdd(&cursor[d], 1);
        esorted[row_ptr[d] + pos] = src[e];
    }
}

// ---------------- layer 1 fused: gather-mean + h = relu(mean@W1l + b1l + x@W1r) ----------------
__global__ __launch_bounds__(128) void layer1_fused(
    const float* __restrict__ x, const int* __restrict__ row_ptr,
    const int* __restrict__ deg, const int* __restrict__ esorted,
    const float* __restrict__ W1l, const float* __restrict__ b1l,
    const float* __restrict__ W1r, float* __restrict__ h) {
    __shared__ float xs[NPB][C];
    __shared__ float ms[NPB][C];
    int c = threadIdx.x;
    int n0 = blockIdx.x * NPB;
    for (int n = 0; n < NPB; n++) {
        int node = n0 + n;
        if (node >= N_NODES) { xs[n][c] = 0.0f; ms[n][c] = 0.0f; continue; }
        xs[n][c] = x[(size_t)node * C + c];
        int start = row_ptr[node];
        int d = deg[node];
        float acc = 0.0f;
        for (int e = 0; e < d; e++) {
            int s = esorted[start + e];   // wave-uniform -> scalar load
            acc += x[(size_t)s * C + c];  // coalesced 512B row
        }
        ms[n][c] = acc / fmaxf((float)d, 1.0f);
    }
    __syncthreads();
    float bias = b1l[c];
    float acc[NPB];
    #pragma unroll
    for (int n = 0; n < NPB; n++) acc[n] = bias;
    for (int k = 0; k < C; k++) {
        float wl = W1l[k * C + c];
        float wr = W1r[k * C + c];
        #pragma unroll
        for (int n = 0; n < NPB; n++)
            acc[n] = fmaf(ms[n][k], wl, fmaf(xs[n][k], wr, acc[n]));
    }
    #pragma unroll
    for (int n = 0; n < NPB; n++) {
        int node = n0 + n;
        if (node < N_NODES)
            h[(size_t)node * C + c] = fmaxf(acc[n], 0.0f);
    }
}

// ---------------- layer 2 fused: gather-mean + out = mh@W2l + b2l + h@W2r ----------------
__global__ __launch_bounds__(128) void layer2_fused(
    const float* __restrict__ hbuf, const int* __restrict__ row_ptr,
    const int* __restrict__ deg, const int* __restrict__ esorted,
    const float* __restrict__ W2l, const float* __restrict__ b2l,
    const float* __restrict__ W2r, float* __restrict__ out) {
    int c = threadIdx.x;
    int node = blockIdx.x;
    int start = row_ptr[node];
    int d = deg[node];
    float acc = 0.0f;
    for (int e = 0; e < d; e++) {
        int s = esorted[start + e];
        acc += hbuf[(size_t)s * C + c];
    }
    float mh = acc / fmaxf((float)d, 1.0f);
    float hv = hbuf[(size_t)node * C + c];
    float v0 = fmaf(mh, W2l[c * 2 + 0], hv * W2r[c * 2 + 0]);
    float v1 = fmaf(mh, W2l[c * 2 + 1], hv * W2r[c * 2 + 1]);
    __shared__ float red[4];
    int lane = threadIdx.x & 63, wid = threadIdx.x >> 6;
    #pragma unroll
    for (int off = 32; off > 0; off >>= 1) {
        v0 += __shfl_down(v0, off);
        v1 += __shfl_down(v1, off);
    }
    if (lane == 0) { red[wid * 2 + 0] = v0; red[wid * 2 + 1] = v1; }
    __syncthreads();
    if (threadIdx.x == 0) {
        out[node * 2 + 0] = red[0] + red[2] + b2l[0];
        out[node * 2 + 1] = red[1] + red[3] + b2l[1];
    }
}

extern "C" void kernel_launch(void* const* d_in, const int* in_sizes, int n_in,
                              void* d_out, int out_size, void* d_ws, size_t ws_size,
                              hipStream_t stream) {
    const float* x   = (const float*)d_in[0];
    const int*   ei  = (const int*)d_in[1];   // (2, 800000) row-major
    const float* W1l = (const float*)d_in[2];
    const float* b1l = (const float*)d_in[3];
    const float* W1r = (const float*)d_in[4];
    const float* W2l = (const float*)d_in[5];
    const float* b2l = (const float*)d_in[6];
    const float* W2r = (const float*)d_in[7];
    float* out = (float*)d_out;

    const int* src = ei;
    const int* dst = ei + N_EDGES;

    // workspace layout:
    // deg[50000] | cursor[50000] | row_ptr[50001->50112 pad] | esorted[800000] | h[6.4M floats]
    int* deg     = (int*)d_ws;
    int* cursor  = deg + 50000;
    int* row_ptr = cursor + 50000;
    int* esorted = row_ptr + 50112;
    float* h     = (float*)(esorted + N_EDGES);

    hipMemsetAsync(deg, 0, 50000 * sizeof(int), stream);
    hipMemsetAsync(cursor, 0, 50000 * sizeof(int), stream);

    hist_kernel<<<(N_EDGES + 255) / 256, 256, 0, stream>>>(dst, deg);
    scan_kernel<<<1, 256, 0, stream>>>(deg, row_ptr);
    bucket_kernel<<<(N_EDGES + 255) / 256, 256, 0, stream>>>(src, dst, row_ptr, cursor, esorted);

    layer1_fused<<<(N_NODES + NPB - 1) / NPB, 128, 0, stream>>>(
        x, row_ptr, deg, esorted, W1l, b1l, W1r, h);
    layer2_fused<<<N_NODES, 128, 0, stream>>>(
        h, row_ptr, deg, esorted, W2l, b2l, W2r, out);
}

// Round 3
// 411.199 us; speedup vs baseline: 7.1718x; 1.3825x over previous
//
#include <hip/hip_runtime.h>

#define N_NODES 50000
#define N_EDGES 800000
#define C 128
#define NPB 8  // nodes per block in layer1 (50000 % 8 == 0 -> 6250 blocks, no bounds checks)

// ---------------- degree histogram (int) ----------------
__global__ void hist_kernel(const int* __restrict__ dst, int* __restrict__ deg) {
    int e = blockIdx.x * blockDim.x + threadIdx.x;
    if (e < N_EDGES) atomicAdd(&deg[dst[e]], 1);
}

// ---------------- exclusive scan of deg -> row_ptr (single block) ----------------
__global__ __launch_bounds__(256) void scan_kernel(const int* __restrict__ deg,
                                                   int* __restrict__ row_ptr) {
    __shared__ int sums[256];
    const int PER = (N_NODES + 255) / 256;  // 196
    int t = threadIdx.x;
    int base = t * PER;
    int s = 0;
    for (int i = 0; i < PER; i++) {
        int idx = base + i;
        if (idx < N_NODES) s += deg[idx];
    }
    sums[t] = s;
    __syncthreads();
    for (int off = 1; off < 256; off <<= 1) {
        int v = (t >= off) ? sums[t - off] : 0;
        __syncthreads();
        sums[t] += v;
        __syncthreads();
    }
    int run = (t == 0) ? 0 : sums[t - 1];
    for (int i = 0; i < PER; i++) {
        int idx = base + i;
        if (idx < N_NODES) { row_ptr[idx] = run; run += deg[idx]; }
    }
    if (t == 255) row_ptr[N_NODES] = run;
}

// ---------------- bucket fill: esorted[row_ptr[d] + pos] = src ----------------
__global__ void bucket_kernel(const int* __restrict__ src, const int* __restrict__ dst,
                              const int* __restrict__ row_ptr, int* __restrict__ cursor,
                              int* __restrict__ esorted) {
    int e = blockIdx.x * blockDim.x + threadIdx.x;
    if (e < N_EDGES) {
        int d = dst[e];
        int pos = atomicAdd(&cursor[d], 1);
        esorted[row_ptr[d] + pos] = src[e];
    }
}

__device__ __forceinline__ void acc4(float4& a, const float4 v) {
    a.x += v.x; a.y += v.y; a.z += v.z; a.w += v.w;
}

// gather mean of feat rows listed in esorted[start..start+d) into m4 (this thread's
// float4 slice q of the row), 4-deep ILP
__device__ __forceinline__ float4 gather_mean(const float* __restrict__ feat,
                                              const int* __restrict__ esorted,
                                              int start, int d, int q) {
    float4 a0 = {0,0,0,0}, a1 = {0,0,0,0}, a2 = {0,0,0,0}, a3 = {0,0,0,0};
    int e = 0;
    for (; e + 4 <= d; e += 4) {
        int s0 = esorted[start + e + 0];
        int s1 = esorted[start + e + 1];
        int s2 = esorted[start + e + 2];
        int s3 = esorted[start + e + 3];
        float4 v0 = ((const float4*)(feat + (size_t)s0 * C))[q];
        float4 v1 = ((const float4*)(feat + (size_t)s1 * C))[q];
        float4 v2 = ((const float4*)(feat + (size_t)s2 * C))[q];
        float4 v3 = ((const float4*)(feat + (size_t)s3 * C))[q];
        acc4(a0, v0); acc4(a1, v1); acc4(a2, v2); acc4(a3, v3);
    }
    for (; e < d; e++) {
        int s = esorted[start + e];
        acc4(a0, ((const float4*)(feat + (size_t)s * C))[q]);
    }
    float inv = 1.0f / fmaxf((float)d, 1.0f);
    float4 m;
    m.x = (a0.x + a1.x + a2.x + a3.x) * inv;
    m.y = (a0.y + a1.y + a2.y + a3.y) * inv;
    m.z = (a0.z + a1.z + a2.z + a3.z) * inv;
    m.w = (a0.w + a1.w + a2.w + a3.w) * inv;
    return m;
}

// ---------------- layer 1 fused: gather-mean + h = relu(mean@W1l + b1l + x@W1r) ----------------
// Gather phase: 32 threads per row (float4/lane), 4 nodes concurrently, 2 passes.
// GEMM phase: 128 threads = one per output column, 8 nodes register-blocked.
__global__ __launch_bounds__(128) void layer1_fused(
    const float* __restrict__ x, const int* __restrict__ row_ptr,
    const int* __restrict__ deg, const int* __restrict__ esorted,
    const float* __restrict__ W1l, const float* __restrict__ b1l,
    const float* __restrict__ W1r, float* __restrict__ h) {
    __shared__ float xs[NPB][C];
    __shared__ float ms[NPB][C];
    int t = threadIdx.x;
    int n0 = blockIdx.x * NPB;
    int rq = t >> 5;     // row slot 0..3
    int q  = t & 31;     // float4 index within row
    #pragma unroll
    for (int half = 0; half < NPB / 4; half++) {
        int n = half * 4 + rq;
        int node = n0 + n;
        ((float4*)xs[n])[q] = ((const float4*)(x + (size_t)node * C))[q];
        int start = row_ptr[node];
        int d = deg[node];
        ((float4*)ms[n])[q] = gather_mean(x, esorted, start, d, q);
    }
    __syncthreads();
    int c = t;
    float bias = b1l[c];
    float acc[NPB];
    #pragma unroll
    for (int n = 0; n < NPB; n++) acc[n] = bias;
    for (int k = 0; k < C; k++) {
        float wl = W1l[k * C + c];
        float wr = W1r[k * C + c];
        #pragma unroll
        for (int n = 0; n < NPB; n++)
            acc[n] = fmaf(ms[n][k], wl, fmaf(xs[n][k], wr, acc[n]));
    }
    #pragma unroll
    for (int n = 0; n < NPB; n++)
        h[(size_t)(n0 + n) * C + c] = fmaxf(acc[n], 0.0f);
}

// ---------------- layer 2 fused: gather-mean + out = mh@W2l + b2l + h@W2r ----------------
// 256 threads = 8 nodes/block x 32 threads/node (float4 per lane).
__global__ __launch_bounds__(256) void layer2_fused(
    const float* __restrict__ hbuf, const int* __restrict__ row_ptr,
    const int* __restrict__ deg, const int* __restrict__ esorted,
    const float* __restrict__ W2l, const float* __restrict__ b2l,
    const float* __restrict__ W2r, float* __restrict__ out) {
    int t = threadIdx.x;
    int g = t >> 5;      // node slot 0..7
    int q = t & 31;
    int node = blockIdx.x * 8 + g;   // 50000 % 8 == 0 -> 6250 blocks
    int start = row_ptr[node];
    int d = deg[node];
    float4 mh = gather_mean(hbuf, esorted, start, d, q);
    float4 hv = ((const float4*)(hbuf + (size_t)node * C))[q];
    // W2l/W2r are (128,2) row-major; this lane covers k = 4q..4q+3 -> 8 floats each
    const float4* wl4 = (const float4*)(W2l + q * 8);
    const float4* wr4 = (const float4*)(W2r + q * 8);
    float4 la = wl4[0], lb = wl4[1];  // [k0c0,k0c1,k1c0,k1c1], [k2c0,k2c1,k3c0,k3c1]
    float4 ra = wr4[0], rb = wr4[1];
    float v0 = mh.x * la.x + mh.y * la.z + mh.z * lb.x + mh.w * lb.z
             + hv.x * ra.x + hv.y * ra.z + hv.z * rb.x + hv.w * rb.z;
    float v1 = mh.x * la.y + mh.y * la.w + mh.z * lb.y + mh.w * lb.w
             + hv.x * ra.y + hv.y * ra.w + hv.z * rb.y + hv.w * rb.w;
    #pragma unroll
    for (int off = 16; off > 0; off >>= 1) {
        v0 += __shfl_down(v0, off);
        v1 += __shfl_down(v1, off);
    }
    if (q == 0) {
        out[node * 2 + 0] = v0 + b2l[0];
        out[node * 2 + 1] = v1 + b2l[1];
    }
}

extern "C" void kernel_launch(void* const* d_in, const int* in_sizes, int n_in,
                              void* d_out, int out_size, void* d_ws, size_t ws_size,
                              hipStream_t stream) {
    const float* x   = (const float*)d_in[0];
    const int*   ei  = (const int*)d_in[1];   // (2, 800000) row-major
    const float* W1l = (const float*)d_in[2];
    const float* b1l = (const float*)d_in[3];
    const float* W1r = (const float*)d_in[4];
    const float* W2l = (const float*)d_in[5];
    const float* b2l = (const float*)d_in[6];
    const float* W2r = (const float*)d_in[7];
    float* out = (float*)d_out;

    const int* src = ei;
    const int* dst = ei + N_EDGES;

    // workspace layout:
    // deg[50000] | cursor[50000] | row_ptr[50112 pad] | esorted[800000] | h[6.4M floats]
    int* deg     = (int*)d_ws;
    int* cursor  = deg + 50000;
    int* row_ptr = cursor + 50000;
    int* esorted = row_ptr + 50112;
    float* h     = (float*)(esorted + N_EDGES);

    hipMemsetAsync(deg, 0, 50000 * sizeof(int), stream);
    hipMemsetAsync(cursor, 0, 50000 * sizeof(int), stream);

    hist_kernel<<<(N_EDGES + 255) / 256, 256, 0, stream>>>(dst, deg);
    scan_kernel<<<1, 256, 0, stream>>>(deg, row_ptr);
    bucket_kernel<<<(N_EDGES + 255) / 256, 256, 0, stream>>>(src, dst, row_ptr, cursor, esorted);

    layer1_fused<<<N_NODES / NPB, 128, 0, stream>>>(
        x, row_ptr, deg, esorted, W1l, b1l, W1r, h);
    layer2_fused<<<N_NODES / 8, 256, 0, stream>>>(
        h, row_ptr, deg, esorted, W2l, b2l, W2r, out);
}